// Round 2
// baseline (189.296 us; speedup 1.0000x reference)
//
#include <hip/hip_runtime.h>
#include <hip/hip_bf16.h>

#define DIM  512
#define FEAT 64
#define BATCH 2048

#define ROWS_PER_BLOCK 256
#define TILES_PER_WAVE 4   // ROWS_PER_BLOCK / (4 waves * 16 rows)

using bf16x8 = __attribute__((ext_vector_type(8))) short;
using f32x4  = __attribute__((ext_vector_type(4))) float;

__device__ inline short f2bf(float f) {
    // round-to-nearest-even fp32 -> bf16
    unsigned int u = __float_as_uint(f);
    u += 0x7fffu + ((u >> 16) & 1u);
    return (short)(u >> 16);
}

__device__ inline bf16x8 cvt8(float4 a, float4 b) {
    bf16x8 r;
    r[0] = f2bf(a.x); r[1] = f2bf(a.y); r[2] = f2bf(a.z); r[3] = f2bf(a.w);
    r[4] = f2bf(b.x); r[5] = f2bf(b.y); r[6] = f2bf(b.z); r[7] = f2bf(b.w);
    return r;
}

__global__ __launch_bounds__(256, 4)
void split_linear_kernel(const float* __restrict__ x,
                         const float* __restrict__ W,
                         const float* __restrict__ bias,
                         float* __restrict__ out)
{
    const int d    = blockIdx.y;
    const int b0   = blockIdx.x * ROWS_PER_BLOCK;
    const int tid  = threadIdx.x;
    const int wave = tid >> 6;
    const int lane = tid & 63;
    const int lr   = lane & 15;   // A-row (g) / B-col (batch) / D-col (batch)
    const int lk   = lane >> 4;   // k-group / D row-quad

    // ---- A-operand: W fragments. A[i][k] = W[d][g = mt*16+lr][k = ks*32+lk*8+j] ----
    bf16x8 wf[2][4];
#pragma unroll
    for (int mt = 0; mt < 4; ++mt) {
        const float* wrow = W + ((size_t)d * FEAT + mt * 16 + lr) * FEAT + lk * 8;
#pragma unroll
        for (int ks = 0; ks < 2; ++ks) {
            float4 w0 = *(const float4*)(wrow + ks * 32);
            float4 w1 = *(const float4*)(wrow + ks * 32 + 4);
            wf[ks][mt] = cvt8(w0, w1);
        }
    }

    // ---- bias as accumulator init: D row g = mt*16 + lk*4 + r ----
    f32x4 bias4[4];
#pragma unroll
    for (int mt = 0; mt < 4; ++mt)
        bias4[mt] = *(const f32x4*)(bias + (size_t)d * FEAT + mt * 16 + lk * 4);

    // ---- software-pipelined main loop over 16-row batch tiles ----
    // B-operand: B[k][j] = x[b0 + tt*16 + j][d][k], lane j = lr, k = ks*32+lk*8+jj
    float4 raw[2][4];
    {
        const float* xp = x + ((size_t)(b0 + wave * 16 + lr) * DIM + d) * FEAT + lk * 8;
        raw[0][0] = *(const float4*)(xp);
        raw[0][1] = *(const float4*)(xp + 4);
        raw[0][2] = *(const float4*)(xp + 32);
        raw[0][3] = *(const float4*)(xp + 36);
    }

#pragma unroll
    for (int t = 0; t < TILES_PER_WAVE; ++t) {
        const int cur = t & 1, nxt = cur ^ 1;
        if (t + 1 < TILES_PER_WAVE) {
            const float* xp = x + ((size_t)(b0 + ((t + 1) * 4 + wave) * 16 + lr) * DIM + d) * FEAT + lk * 8;
            raw[nxt][0] = *(const float4*)(xp);
            raw[nxt][1] = *(const float4*)(xp + 4);
            raw[nxt][2] = *(const float4*)(xp + 32);
            raw[nxt][3] = *(const float4*)(xp + 36);
        }

        bf16x8 af0 = cvt8(raw[cur][0], raw[cur][1]);   // ks = 0
        bf16x8 af1 = cvt8(raw[cur][2], raw[cur][3]);   // ks = 1

        f32x4 acc[4];
#pragma unroll
        for (int mt = 0; mt < 4; ++mt) acc[mt] = bias4[mt];
#pragma unroll
        for (int mt = 0; mt < 4; ++mt)
            acc[mt] = __builtin_amdgcn_mfma_f32_16x16x32_bf16(wf[0][mt], af0, acc[mt], 0, 0, 0);
#pragma unroll
        for (int mt = 0; mt < 4; ++mt)
            acc[mt] = __builtin_amdgcn_mfma_f32_16x16x32_bf16(wf[1][mt], af1, acc[mt], 0, 0, 0);

        // ---- store: lane owns out[b0+tt*16+lr][d][mt*16 + lk*4 .. +3] (float4) ----
        float* op = out + ((size_t)(b0 + (t * 4 + wave) * 16 + lr) * DIM + d) * FEAT + lk * 4;
#pragma unroll
        for (int mt = 0; mt < 4; ++mt)
            __builtin_nontemporal_store(acc[mt], (f32x4*)(op + mt * 16));
    }
}

extern "C" void kernel_launch(void* const* d_in, const int* in_sizes, int n_in,
                              void* d_out, int out_size, void* d_ws, size_t ws_size,
                              hipStream_t stream) {
    const float* x    = (const float*)d_in[0];
    const float* W    = (const float*)d_in[1];
    const float* bias = (const float*)d_in[2];
    float* out        = (float*)d_out;

    dim3 grid(BATCH / ROWS_PER_BLOCK, DIM, 1);  // (8, 512)
    dim3 block(256, 1, 1);
    split_linear_kernel<<<grid, block, 0, stream>>>(x, W, bias, out);
}